// Round 4
// baseline (212.327 us; speedup 1.0000x reference)
//
#include <hip/hip_runtime.h>
#include <stdint.h>

#define SCORE_THRESH 0.05f
#define IOU_THRESH 0.5f
#define TOP_K 1000
#define MAX_DET 100

#define D0_BITS 13
#define D0_BINS 8192           // 2^13
#define NREP 4                 // replicated pass-0 histograms
#define CAND_CAP 2048
#define NSURV 64               // blocks surviving past S1 (multiple of 8)

typedef unsigned int u32;
typedef unsigned long long u64;

// ---- ws layout (bytes) ----
// [hist0][hist1][state][bar] is one contiguous host-memset region.
#define OFF_HIST0    0          // u32[NREP*8192] = 131072
#define OFF_HIST1    131072     // u32[65536] = 262144 -> 393216
#define OFF_STATE    393216     // u32 slots, each padded to its own 128B line:
                                //   slot0=k_rem slot1=d0cut slot2=d1cut slot5=cand_cnt
#define OFF_BAR      394240     // 7 barriers x 4096B tree region -> 427008
#define MEMSET_LEN   427008
#define OFF_CAND     427008     // u32[2048] -> 435200
#define OFF_RFLAG    435200     // u32[1000] -> 439200
#define OFF_SIDX     439200     // u32[1000] -> 443200
#define OFF_SSCORE   443200     // float[1000] -> 447200
#define OFF_CBOX     447200     // float[4000] -> 463200 (16B aligned)
#define OFF_M        463200     // u64[1000*16] = 128000 -> 591200 (8B aligned)
#define OFF_SCORES   591200     // float[A]

#define BAR_STRIDE_U32 1024     // 4KB per barrier: grp lines 0..7, root line 8, go lines 16..23

__device__ __forceinline__ u32 order_f32(float f) {
    u32 b = __float_as_uint(f);
    return (b & 0x80000000u) ? ~b : (b | 0x80000000u);
}

// MALL-direct (sc1) accessors: relaxed agent-scope atomics carry no fence, so
// NO buffer_wbl2 / buffer_inv is ever emitted. Stores write through to the
// coherence point without allocating L1/L2; loads bypass stale caches.
__device__ __forceinline__ void st_sc(u32* p, u32 v)   { __hip_atomic_store(p, v, __ATOMIC_RELAXED, __HIP_MEMORY_SCOPE_AGENT); }
__device__ __forceinline__ void st_sc(float* p, float v){ __hip_atomic_store(p, v, __ATOMIC_RELAXED, __HIP_MEMORY_SCOPE_AGENT); }
__device__ __forceinline__ void st_sc(u64* p, u64 v)   { __hip_atomic_store(p, v, __ATOMIC_RELAXED, __HIP_MEMORY_SCOPE_AGENT); }
__device__ __forceinline__ u32  ld_sc(u32* p)          { return __hip_atomic_load(p, __ATOMIC_RELAXED, __HIP_MEMORY_SCOPE_AGENT); }

// Device-wide barrier with ZERO cache-maintenance ops.
// R1 lesson: acquire-load spin -> buffer_inv per poll -> 620us.
// R2 lesson: release RMW (wbl2) + acquire fence (inv) per block-barrier -> 271us.
// R3 lesson: zero-maintenance tree barrier works (100us) but 512-way fan-in
// x7 barriers is ~half the remaining time -> this round: 64 survivors only.
// Correctness: __syncthreads' per-wave vmcnt drain + explicit vmcnt(0) puts
// all this block's sc1 stores at the coherence point before arrival; readers
// first-touch lines only after the producing barrier (layout discipline).
// gsz = arrivals per group (g = b&7).
__device__ __forceinline__ void gbar(u32* barr, int k, int b, u32 gsz, bool dowait) {
    __syncthreads();
    if (threadIdx.x == 0) {
        asm volatile("s_waitcnt vmcnt(0)" ::: "memory");
        u32* base = barr + (size_t)k * BAR_STRIDE_U32;
        int g = b & 7;
        if (__hip_atomic_fetch_add(base + g * 32, 1u, __ATOMIC_RELAXED,
                                   __HIP_MEMORY_SCOPE_AGENT) == gsz - 1u) {
            if (__hip_atomic_fetch_add(base + 8 * 32, 1u, __ATOMIC_RELAXED,
                                       __HIP_MEMORY_SCOPE_AGENT) == 7u) {
                #pragma unroll
                for (int g2 = 0; g2 < 8; g2++)
                    st_sc(base + (16 + g2) * 32, 1u);
            }
        }
        if (dowait) {
            while (ld_sc(base + (16 + g) * 32) == 0u)
                __builtin_amdgcn_s_sleep(8);
        }
        asm volatile("" ::: "memory");
    }
    __syncthreads();
}

union ShMem {
    u32 hl[D0_BINS / 2];                               // 16 KB — S1 LDS histogram (u16-packed)
    u32 wtot[4];                                       // S2/S4 wave totals
    struct { u32 wcnt[4]; u32 wbase[4]; u32 bbase; } cmp;  // S5 compact
    struct { u64 ckeys[8]; u32 wpart[4][8]; } rank;    // S6
    struct {
        u64 Ml[256 * 16];                              // 32 KB active-row mask chunk
        u64 keepS[16];
        u32 nib[256];
        int act[TOP_K];
        u32 wsum[4];
        int nactS;
        int det[MAX_DET];
    } nms;                                             // ~38.3 KB total
};

__global__ void __launch_bounds__(256, 2)
mega(const float* __restrict__ cls, const float* __restrict__ regs,
     const float* __restrict__ anchors, const int* __restrict__ pH,
     const int* __restrict__ pW, int A, int C,
     char* __restrict__ ws, float* __restrict__ out)
{
    __shared__ ShMem sh;
    u32*   hist0  = (u32*)(ws + OFF_HIST0);
    u32*   hist1  = (u32*)(ws + OFF_HIST1);
    u32*   state  = (u32*)(ws + OFF_STATE);   // slot i at state[i*32] (own 128B line)
    u32*   barr   = (u32*)(ws + OFF_BAR);
    u32*   cand   = (u32*)(ws + OFF_CAND);
    u32*   rflag  = (u32*)(ws + OFF_RFLAG);
    u32*   sidx   = (u32*)(ws + OFF_SIDX);
    float* sscore = (float*)(ws + OFF_SSCORE);
    float* cbox   = (float*)(ws + OFF_CBOX);
    u64*   M      = (u64*)(ws + OFF_M);
    float* scores = (float*)(ws + OFF_SCORES);

    const int t = threadIdx.x;
    const int b = blockIdx.x;
    const int G = gridDim.x;
    const int gid = b * 256 + t;
    const int gstride = G * 256;
    const int lane = t & 63, wv = t >> 6;

    // ---------- S1: coalesced class-max + thresholded score + pass-0 hist ----------
    // hist0/hist1/state/bar were zeroed by the host memset (prior dispatch).
    if (C == 80) {
        for (int i = t; i < D0_BINS / 2; i += 256) sh.hl[i] = 0;
        __syncthreads();
        int sub = t & 3;           // which 20-float quarter of the 80 classes
        int la  = t >> 2;          // local anchor 0..63
        int nstrips = (A + 63) >> 6;
        int per = (nstrips + G - 1) / G;
        for (int s = 0; s < per; s++) {
            int a = (b * per + s) * 64 + la;
            float m = -1e30f;
            if (a < A) {
                const float* p = cls + (size_t)a * 80 + sub * 4;
                #pragma unroll
                for (int k2 = 0; k2 < 5; k2++) {
                    float4 v = *(const float4*)(p + k2 * 16);
                    m = fmaxf(m, fmaxf(fmaxf(v.x, v.y), fmaxf(v.z, v.w)));
                }
            }
            m = fmaxf(m, __shfl_xor(m, 1, 64));
            m = fmaxf(m, __shfl_xor(m, 2, 64));
            if (sub == 0 && a < A) {
                float s0 = (m > SCORE_THRESH) ? m : -1.0f;
                st_sc(&scores[a], s0);                  // sc1: visible at MALL
                u32 d = order_f32(s0) >> (32 - D0_BITS);
                atomicAdd(&sh.hl[d >> 1], (d & 1) ? 0x10000u : 1u);
            }
        }
        __syncthreads();
        u32* rep = hist0 + (size_t)(b & (NREP - 1)) * D0_BINS;
        for (int i = t; i < D0_BINS / 2; i += 256) {
            u32 v = sh.hl[i];
            if (v & 0xFFFFu) atomicAdd(&rep[2 * i],     v & 0xFFFFu);   // memory-side RMW
            if (v >> 16)     atomicAdd(&rep[2 * i + 1], v >> 16);
        }
    } else {
        u32* rep = hist0 + (size_t)(b & (NREP - 1)) * D0_BINS;
        for (int a = gid; a < A; a += gstride) {
            const float* p = cls + (size_t)a * C;
            float m = -1e30f;
            for (int c = 0; c < C; c++) m = fmaxf(m, p[c]);
            st_sc(&scores[a], (m > SCORE_THRESH) ? m : -1.0f);
            atomicAdd(&rep[order_f32((m > SCORE_THRESH) ? m : -1.0f) >> (32 - D0_BITS)], 1u);
        }
    }
    // bar0: all G blocks arrive (drains their S1 stores); only survivors wait.
    {
        bool surv = (b < NSURV);
        gbar(barr, 0, b, (u32)(G / 8), surv);
        if (!surv) return;          // 448 blocks exit; all later barriers are 64-wide
    }

    const int gid2 = b * 256 + t;
    const int gstride2 = NSURV * 256;

    // ---------- S2: scan0 (block 0): d0 cut bin for k=TOP_K ----------
    if (b == 0) {
        u32 cnt[32];
        #pragma unroll
        for (int i = 0; i < 32; i++) cnt[i] = 0;
        const uint4* hp = (const uint4*)hist0;
        #pragma unroll
        for (int r = 0; r < NREP; r++) {
            #pragma unroll
            for (int i = 0; i < 8; i++) {
                uint4 v = hp[r * (D0_BINS / 4) + t * 8 + i];
                cnt[4*i]   += v.x; cnt[4*i+1] += v.y;
                cnt[4*i+2] += v.z; cnt[4*i+3] += v.w;
            }
        }
        u32 s = 0;
        #pragma unroll
        for (int i = 0; i < 32; i++) s += cnt[i];
        u32 x = s;   // suffix-inclusive within wave (higher lane = higher bins)
        for (int off = 1; off < 64; off <<= 1) {
            u32 v = (u32)__shfl_down((int)x, off, 64);
            if (lane + off < 64) x += v;
        }
        if (lane == 0) sh.wtot[wv] = x;
        __syncthreads();
        u32 above = x - s;
        for (int w = wv + 1; w < 4; w++) above += sh.wtot[w];
        if (above < TOP_K && above + s >= TOP_K) {
            u32 cum = above;
            for (int i = 31; i >= 0; i--) {
                cum += cnt[i];
                if (cum >= TOP_K) {
                    st_sc(&state[1 * 32], (u32)(t * 32 + i));
                    st_sc(&state[0 * 32], TOP_K - (cum - cnt[i]));
                    break;
                }
            }
        }
    }
    // Prefetch this block's S3/S5 score slice into L1/L2 while block 0 scans.
    // Safe: bar0-go => every block's sc1 score stores reached the coherence
    // point; scores are read-only from here on.
    {
        float acc = 0.0f;
        for (int a = gid2; a < A; a += gstride2) acc += scores[a];
        asm volatile("" :: "v"(acc));     // keep the loads alive
    }
    gbar(barr, 1, b, NSURV / 8, true);       // everyone needs d0cut

    // ---------- S3: pass-1 histogram (bits [18:3] of keys in cut d0 bin) ----------
    {
        u32 d0cut = state[1 * 32];           // first cached read of this line
        for (int a = gid2; a < A; a += gstride2) {
            u32 key = order_f32(scores[a]);  // L1/L2 hit (prefetched)
            if ((key >> (32 - D0_BITS)) == d0cut)
                atomicAdd(&hist1[(key >> 3) & 0xFFFFu], 1u);
        }
    }
    gbar(barr, 2, b, NSURV / 8, b == 0);     // only block 0 (S4) consumes hist1

    // ---------- S4: scan1 (block 0): d1 cut for k=k_rem ----------
    if (b == 0) {
        u32 k = state[0 * 32];
        const uint4* hp = (const uint4*)hist1;  // strip = bins [t*256, t*256+256)
        u32 chk[8]; u32 s = 0;
        #pragma unroll
        for (int c = 0; c < 8; c++) {
            u32 cs = 0;
            #pragma unroll
            for (int i = 0; i < 8; i++) {
                uint4 v = hp[t * 64 + c * 8 + i];
                cs += v.x + v.y + v.z + v.w;
            }
            chk[c] = cs; s += cs;
        }
        u32 x = s;
        for (int off = 1; off < 64; off <<= 1) {
            u32 v = (u32)__shfl_down((int)x, off, 64);
            if (lane + off < 64) x += v;
        }
        if (lane == 0) sh.wtot[wv] = x;
        __syncthreads();
        u32 above = x - s;
        for (int w = wv + 1; w < 4; w++) above += sh.wtot[w];
        if (above < k && above + s >= k) {
            u32 cum = above;
            bool done = false;
            for (int c = 7; c >= 0 && !done; c--) {
                if (cum + chk[c] >= k) {        // cut is inside chunk c
                    for (int i = 7; i >= 0 && !done; i--) {
                        uint4 v = hp[t * 64 + c * 8 + i];
                        u32 vv[4] = {v.x, v.y, v.z, v.w};
                        for (int q = 3; q >= 0 && !done; q--) {
                            cum += vv[q];
                            if (cum >= k) {
                                st_sc(&state[2 * 32], (u32)(t * 256 + c * 32 + i * 4 + q));
                                done = true;
                            }
                        }
                    }
                } else cum += chk[c];
            }
        }
    }
    gbar(barr, 3, b, NSURV / 8, true);       // everyone needs d1cut

    // ---------- S5: compact (pfx29 >= cut), per-block aggregated reservation ----------
    {
        u32 cut = (state[1 * 32] << 16) | state[2 * 32];
        int nr = (A + gstride2 - 1) / gstride2;
        for (int r = 0; r < nr; r++) {
            int a = gid2 + r * gstride2;
            bool pass = (a < A) && ((order_f32(scores[a]) >> 3) >= cut);
            u64 mask = __ballot(pass ? 1 : 0);
            if (lane == 0) sh.cmp.wcnt[wv] = (u32)__popcll(mask);
            __syncthreads();
            if (t == 0) {
                u32 s = 0;
                #pragma unroll
                for (int w = 0; w < 4; w++) { sh.cmp.wbase[w] = s; s += sh.cmp.wcnt[w]; }
                sh.cmp.bbase = s ? atomicAdd(&state[5 * 32], s) : 0u;
            }
            __syncthreads();
            if (pass) {
                u32 pos = sh.cmp.bbase + sh.cmp.wbase[wv]
                        + (u32)__popcll(mask & ((1ull << lane) - 1ull));
                if (pos < CAND_CAP) st_sc(&cand[pos], (u32)a);
            }
            __syncthreads();
        }
    }
    gbar(barr, 4, b, NSURV / 8, true);       // all survivors participate in S6

    // ---------- S6: exact parallel rank + decode ----------
    {
        int n = (int)state[5 * 32]; if (n > CAND_CAP) n = CAND_CAP;   // first-touch
        u64 kj[8];                           // bb-invariant: load once per block
        #pragma unroll
        for (int q = 0; q < 8; q++) {
            int j = t * 8 + q;
            u64 kk = 0ull;                   // pads never outrank real keys
            if (j < n) {
                u32 a = cand[j];             // first-touch -> MALL, then cached
                kk = ((u64)order_f32(scores[a]) << 32) | (u64)(0xFFFFFFFFu - a);
            }
            kj[q] = kk;
        }
        for (int bb = b; bb < CAND_CAP / 8; bb += NSURV) {
            if (t < 8) {
                int c = bb * 8 + t;
                u64 ck = 0ull;
                if (c < n) {
                    u32 a = cand[c];
                    ck = ((u64)order_f32(scores[a]) << 32) | (u64)(0xFFFFFFFFu - a);
                }
                sh.rank.ckeys[t] = ck;
            }
            __syncthreads();
            u64 ck[8];
            #pragma unroll
            for (int q = 0; q < 8; q++) ck[q] = sh.rank.ckeys[q];
            u32 cnt8[8] = {0,0,0,0,0,0,0,0};
            #pragma unroll
            for (int q = 0; q < 8; q++) {
                u64 kq = kj[q];
                #pragma unroll
                for (int q2 = 0; q2 < 8; q2++) cnt8[q2] += (kq > ck[q2]) ? 1u : 0u;
            }
            #pragma unroll
            for (int q2 = 0; q2 < 8; q2++) {
                u32 x = cnt8[q2];
                x += (u32)__shfl_xor((int)x, 1, 64);
                x += (u32)__shfl_xor((int)x, 2, 64);
                x += (u32)__shfl_xor((int)x, 4, 64);
                x += (u32)__shfl_xor((int)x, 8, 64);
                x += (u32)__shfl_xor((int)x, 16, 64);
                x += (u32)__shfl_xor((int)x, 32, 64);
                if (lane == 0) sh.rank.wpart[wv][q2] = x;
            }
            __syncthreads();
            if (t < 8) {
                int c = bb * 8 + t;
                if (c < n) {
                    u32 rank = sh.rank.wpart[0][t] + sh.rank.wpart[1][t]
                             + sh.rank.wpart[2][t] + sh.rank.wpart[3][t];
                    if (rank < TOP_K) {
                        u32 a = cand[c];
                        st_sc(&sidx[rank], a);
                        st_sc(&sscore[rank], scores[a]);
                        float4 an = *(const float4*)(anchors + (size_t)a * 4);
                        float4 rg = *(const float4*)(regs + (size_t)a * 4);
                        float aw = an.z - an.x, ah = an.w - an.y;
                        float acx = an.x + 0.5f * aw, acy = an.y + 0.5f * ah;
                        float pcx = acx + (rg.x * 0.1f) * aw;
                        float pcy = acy + (rg.y * 0.1f) * ah;
                        float pw = expf(rg.z * 0.2f) * aw;
                        float ph = expf(rg.w * 0.2f) * ah;
                        float W = (float)(*pW), H = (float)(*pH);
                        st_sc(&cbox[rank * 4 + 0], fminf(fmaxf(pcx - 0.5f * pw, 0.0f), W));
                        st_sc(&cbox[rank * 4 + 1], fminf(fmaxf(pcy - 0.5f * ph, 0.0f), H));
                        st_sc(&cbox[rank * 4 + 2], fminf(fmaxf(pcx + 0.5f * pw, 0.0f), W));
                        st_sc(&cbox[rank * 4 + 3], fminf(fmaxf(pcy + 0.5f * ph, 0.0f), H));
                    }
                }
            }
            __syncthreads();
        }
    }
    gbar(barr, 5, b, NSURV / 8, true);       // all survivors participate in S7

    // ---------- S7: IoU suppression bit-matrix (wave per row) ----------
    {
        const float4* B4 = (const float4*)cbox;   // first-touch -> MALL, then cached
        for (int i = b * 4 + wv; i < TOP_K; i += NSURV * 4) {
            float4 bi = B4[i];
            float ai = fmaxf(bi.z - bi.x, 0.0f) * fmaxf(bi.w - bi.y, 0.0f);
            u64 any = 0ull;
            for (int w = 0; w < 16; w++) {
                int j = w * 64 + lane;
                bool sup = false;
                if (j < TOP_K && j > i) {
                    float4 bj = B4[j];
                    float aj = fmaxf(bj.z - bj.x, 0.0f) * fmaxf(bj.w - bj.y, 0.0f);
                    float xx1 = fmaxf(bi.x, bj.x), yy1 = fmaxf(bi.y, bj.y);
                    float xx2 = fminf(bi.z, bj.z), yy2 = fminf(bi.w, bj.w);
                    float inter = fmaxf(xx2 - xx1, 0.0f) * fmaxf(yy2 - yy1, 0.0f);
                    float iou = inter / (ai + aj - inter + 1e-8f);
                    sup = iou > IOU_THRESH;
                }
                u64 mask = __ballot(sup ? 1 : 0);
                if (lane == 0) { st_sc(&M[(size_t)i * 16 + w], mask); any |= mask; }
            }
            if (lane == 0) st_sc(&rflag[i], (any != 0ull) ? 1u : 0u);
        }
    }
    gbar(barr, 6, b, NSURV / 8, b == 0);     // only block 0 (S8) consumes

    // ---------- S8: greedy NMS over active rows + finalize (block 0) ----------
    if (b == 0) {
        {
            u32 nb = 0;
            int j0 = 4 * t;
            #pragma unroll
            for (int q = 0; q < 4; q++) {
                int j = j0 + q;
                if (j < TOP_K && sscore[j] > SCORE_THRESH) nb |= (1u << q);
            }
            sh.nms.nib[t] = nb;
        }
        u32 flags = 0; int cnt = 0;
        {
            int r0 = 4 * t;
            #pragma unroll
            for (int q = 0; q < 4; q++) {
                int r = r0 + q;
                if (r < TOP_K && rflag[r]) { flags |= (1u << q); cnt++; }
            }
        }
        int x = cnt;
        for (int off = 1; off < 64; off <<= 1) {
            int v = __shfl_up(x, off, 64);
            if (lane >= off) x += v;
        }
        if (lane == 63) sh.nms.wsum[wv] = (u32)x;
        __syncthreads();
        if (t < 16) {
            u64 w = 0;
            for (int m2 = 0; m2 < 16; m2++)
                w |= ((u64)sh.nms.nib[t * 16 + m2]) << (4 * m2);
            sh.nms.keepS[t] = w;
        }
        int base = 0;
        for (int w = 0; w < wv; w++) base += (int)sh.nms.wsum[w];
        int pos = base + x - cnt;
        {
            int r0 = 4 * t;
            #pragma unroll
            for (int q = 0; q < 4; q++)
                if (flags & (1u << q)) sh.nms.act[pos++] = r0 + q;
        }
        if (t == 0) {
            int na = 0;
            for (int w = 0; w < 4; w++) na += (int)sh.nms.wsum[w];
            sh.nms.nactS = na;
        }
        __syncthreads();
        int nact = sh.nms.nactS;

        for (int c0 = 0; c0 < nact; c0 += 256) {
            int cn = (nact - c0 < 256) ? (nact - c0) : 256;
            for (int i = t; i < cn * 16; i += 256) {
                int row = sh.nms.act[c0 + (i >> 4)];
                sh.nms.Ml[i] = M[(size_t)row * 16 + (i & 15)];
            }
            __syncthreads();
            if (wv == 0) {
                u64 kp = (lane < 16) ? sh.nms.keepS[lane] : 0ull;
                for (int k = 0; k < cn; k++) {
                    int i = sh.nms.act[c0 + k];
                    u64 kw = __shfl(kp, i >> 6, 64);
                    if ((kw >> (i & 63)) & 1ull) {
                        u64 m2 = (lane < 16) ? sh.nms.Ml[k * 16 + lane] : 0ull;
                        kp &= ~m2;
                    }
                }
                if (lane < 16) sh.nms.keepS[lane] = kp;
            }
            __syncthreads();
        }

        if (t == 0) {
            int cnt2 = 0;
            for (int w = 0; w < 16 && cnt2 < MAX_DET; w++) {
                u64 kw = sh.nms.keepS[w];
                while (kw && cnt2 < MAX_DET) {
                    int bbit = __ffsll((unsigned long long)kw) - 1;
                    sh.nms.det[cnt2++] = w * 64 + bbit;
                    kw &= kw - 1;
                }
            }
            for (; cnt2 < MAX_DET; cnt2++) sh.nms.det[cnt2] = -1;
        }
        __syncthreads();
        if (t < MAX_DET) {
            int i = sh.nms.det[t];
            if (i >= 0) {
                u32 a = sidx[i];
                const float* p = cls + (size_t)a * C;
                float best = -1e30f; int bc = 0;
                if (C == 80) {
                    #pragma unroll
                    for (int c4 = 0; c4 < 20; c4++) {
                        float4 v = *(const float4*)(p + c4 * 4);
                        if (v.x > best) { best = v.x; bc = c4 * 4; }
                        if (v.y > best) { best = v.y; bc = c4 * 4 + 1; }
                        if (v.z > best) { best = v.z; bc = c4 * 4 + 2; }
                        if (v.w > best) { best = v.w; bc = c4 * 4 + 3; }
                    }
                } else {
                    best = p[0]; bc = 0;
                    for (int c = 1; c < C; c++) {
                        float v = p[c];
                        if (v > best) { best = v; bc = c; }
                    }
                }
                out[t] = best;
                out[MAX_DET + t] = (float)bc;
                out[2 * MAX_DET + t * 4 + 0] = cbox[i * 4 + 0];
                out[2 * MAX_DET + t * 4 + 1] = cbox[i * 4 + 1];
                out[2 * MAX_DET + t * 4 + 2] = cbox[i * 4 + 2];
                out[2 * MAX_DET + t * 4 + 3] = cbox[i * 4 + 3];
            } else {
                out[t] = 0.0f;
                out[MAX_DET + t] = -1.0f;
                out[2 * MAX_DET + t * 4 + 0] = 0.0f;
                out[2 * MAX_DET + t * 4 + 1] = 0.0f;
                out[2 * MAX_DET + t * 4 + 2] = 0.0f;
                out[2 * MAX_DET + t * 4 + 3] = 0.0f;
            }
        }
    }
}

extern "C" void kernel_launch(void* const* d_in, const int* in_sizes, int n_in,
                              void* d_out, int out_size, void* d_ws, size_t ws_size,
                              hipStream_t stream) {
    (void)n_in; (void)out_size; (void)ws_size;
    const float* cls     = (const float*)d_in[0];
    const float* regs    = (const float*)d_in[1];
    const float* anchors = (const float*)d_in[2];
    const int*   pH      = (const int*)d_in[3];
    const int*   pW      = (const int*)d_in[4];
    int A = in_sizes[1] / 4;
    int C = in_sizes[0] / A;

    // grid = 2 blocks/CU, multiple of 8 (barrier tree groups):
    // co-residency guaranteed (38.3KB LDS, launch_bounds(256,2)).
    static int nCU = 0;
    if (nCU <= 0) {
        int dev = 0;
        hipGetDevice(&dev);
        hipDeviceGetAttribute(&nCU, hipDeviceAttributeMultiprocessorCount, dev);
        if (nCU <= 0) nCU = 256;
    }
    int G = (2 * nCU) & ~7;
    if (G < NSURV) G = NSURV;

    char* ws = (char*)d_ws;
    // Zero hist0 + hist1 + state + barrier tree in one memset; the fill
    // dispatch's completion makes the zeros coherence-point visible.
    hipMemsetAsync(ws, 0, MEMSET_LEN, stream);
    mega<<<dim3(G), dim3(256), 0, stream>>>(cls, regs, anchors, pH, pW, A, C,
                                            ws, (float*)d_out);
}

// Round 6
// 180.903 us; speedup vs baseline: 1.1737x; 1.1737x over previous
//
#include <hip/hip_runtime.h>
#include <stdint.h>

#define SCORE_THRESH 0.05f
#define IOU_THRESH 0.5f
#define TOP_K 1000
#define MAX_DET 100

#define D0_BITS 13
#define D0_BINS 8192           // 2^13
#define NREP 4                 // replicated pass-0 histograms
#define CAND_CAP 2048
#define NMS_CHUNK 128          // rows per NMS staging chunk (dbuf: 2x128x16 u64 = 32KB)

typedef unsigned int u32;
typedef unsigned long long u64;

// ---- ws layout (bytes) ----
// [hist0][hist1][state][bar] is one contiguous host-memset region.
#define OFF_HIST0    0          // u32[NREP*8192] = 131072
#define OFF_HIST1    131072     // u32[65536] = 262144 -> 393216
#define OFF_STATE    393216     // u32 slots, each padded to its own 128B line:
                                //   slot0=k_rem slot1=d0cut slot2=d1cut slot5=cand_cnt
#define OFF_BAR      394240     // 7 barriers x 4096B tree region -> 427008
#define MEMSET_LEN   427008
#define OFF_CAND     427008     // u32[2048] -> 435200
#define OFF_RFLAG    435200     // u32[1000] -> 439200
#define OFF_SIDX     439200     // u32[1000] -> 443200
#define OFF_SSCORE   443200     // float[1000] -> 447200
#define OFF_CBOX     447200     // float[4000] -> 463200 (16B aligned)
#define OFF_M        463200     // u64[1000*16] = 128000 -> 591200 (8B aligned)
#define OFF_SCORES   591200     // float[A]

#define BAR_STRIDE_U32 1024     // 4KB per barrier: grp lines 0..7, root line 8, go lines 16..23

__device__ __forceinline__ u32 order_f32(float f) {
    u32 b = __float_as_uint(f);
    return (b & 0x80000000u) ? ~b : (b | 0x80000000u);
}

// MALL-direct (sc1) accessors: relaxed agent-scope atomics carry no fence, so
// NO buffer_wbl2 / buffer_inv is ever emitted. Stores write through to the
// coherence point without allocating L1/L2; loads bypass stale caches.
__device__ __forceinline__ void st_sc(u32* p, u32 v)   { __hip_atomic_store(p, v, __ATOMIC_RELAXED, __HIP_MEMORY_SCOPE_AGENT); }
__device__ __forceinline__ void st_sc(float* p, float v){ __hip_atomic_store(p, v, __ATOMIC_RELAXED, __HIP_MEMORY_SCOPE_AGENT); }
__device__ __forceinline__ void st_sc(u64* p, u64 v)   { __hip_atomic_store(p, v, __ATOMIC_RELAXED, __HIP_MEMORY_SCOPE_AGENT); }
__device__ __forceinline__ u32  ld_sc(u32* p)          { return __hip_atomic_load(p, __ATOMIC_RELAXED, __HIP_MEMORY_SCOPE_AGENT); }

// Device-wide barrier with ZERO cache-maintenance ops.
// R1 lesson: acquire-load spin -> buffer_inv per poll -> 620us.
// R2 lesson: release RMW (wbl2) + acquire fence (inv) per block-barrier -> 271us.
// R3: zero-maintenance tree barrier -> 100us (best).
// R4 lesson: 64 survivor blocks made latency-bound phases 8x less parallel
// -> +50us. Post-S1 time is PHASE latency, not barrier fan-in. Full grid.
// R5 lesson: container failed twice with 69.5KB LDS (only untested change);
// keep LDS at the five-times-proven ~38KB footprint.
// Correctness: explicit vmcnt(0) puts this block's sc1 stores at the
// coherence point before arrival; readers first-touch lines only after the
// producing barrier (layout discipline). gsz = arrivals per group (g = b&7).
__device__ __forceinline__ void gbar(u32* barr, int k, int b, u32 gsz, bool dowait) {
    __syncthreads();
    if (threadIdx.x == 0) {
        asm volatile("s_waitcnt vmcnt(0)" ::: "memory");
        u32* base = barr + (size_t)k * BAR_STRIDE_U32;
        int g = b & 7;
        if (__hip_atomic_fetch_add(base + g * 32, 1u, __ATOMIC_RELAXED,
                                   __HIP_MEMORY_SCOPE_AGENT) == gsz - 1u) {
            if (__hip_atomic_fetch_add(base + 8 * 32, 1u, __ATOMIC_RELAXED,
                                       __HIP_MEMORY_SCOPE_AGENT) == 7u) {
                #pragma unroll
                for (int g2 = 0; g2 < 8; g2++)
                    st_sc(base + (16 + g2) * 32, 1u);
            }
        }
        if (dowait) {
            while (ld_sc(base + (16 + g) * 32) == 0u)
                __builtin_amdgcn_s_sleep(8);
        }
        asm volatile("" ::: "memory");
    }
    __syncthreads();
}

union ShMem {
    u32 hl[D0_BINS / 2];                               // 16 KB — S1 LDS histogram (u16-packed)
    u32 wtot[4];                                       // S2/S4 wave totals
    struct { u32 wcnt[4]; u32 wbase[4]; u32 bbase; } cmp;  // S5 compact
    struct { u64 ckeys[8]; u32 wpart[4][8]; } rank;    // S6
    struct {
        u64 Ml[2 * NMS_CHUNK * 16];                    // 32 KB double-buffered mask chunks
        u64 keepS[16];
        u32 nib[256];
        int act[TOP_K];
        u32 wsum[4];
        int nactS;
        int det[MAX_DET];
    } nms;                                             // ~37.6 KB total (proven footprint)
};

__global__ void __launch_bounds__(256, 2)
mega(const float* __restrict__ cls, const float* __restrict__ regs,
     const float* __restrict__ anchors, const int* __restrict__ pH,
     const int* __restrict__ pW, int A, int C,
     char* __restrict__ ws, float* __restrict__ out)
{
    __shared__ ShMem sh;
    u32*   hist0  = (u32*)(ws + OFF_HIST0);
    u32*   hist1  = (u32*)(ws + OFF_HIST1);
    u32*   state  = (u32*)(ws + OFF_STATE);   // slot i at state[i*32] (own 128B line)
    u32*   barr   = (u32*)(ws + OFF_BAR);
    u32*   cand   = (u32*)(ws + OFF_CAND);
    u32*   rflag  = (u32*)(ws + OFF_RFLAG);
    u32*   sidx   = (u32*)(ws + OFF_SIDX);
    float* sscore = (float*)(ws + OFF_SSCORE);
    float* cbox   = (float*)(ws + OFF_CBOX);
    u64*   M      = (u64*)(ws + OFF_M);
    float* scores = (float*)(ws + OFF_SCORES);

    const int t = threadIdx.x;
    const int b = blockIdx.x;
    const int G = gridDim.x;
    const int gid = b * 256 + t;
    const int gstride = G * 256;
    const int lane = t & 63, wv = t >> 6;
    const u32 gsz = (u32)(G >> 3);

    // ---------- S1: coalesced class-max + thresholded score + pass-0 hist ----------
    // hist0/hist1/state/bar were zeroed by the host memset (prior dispatch).
    if (C == 80) {
        for (int i = t; i < D0_BINS / 2; i += 256) sh.hl[i] = 0;
        __syncthreads();
        int sub = t & 3;           // which 20-float quarter of the 80 classes
        int la  = t >> 2;          // local anchor 0..63
        int nstrips = (A + 63) >> 6;
        int per = (nstrips + G - 1) / G;
        for (int s = 0; s < per; s++) {
            int a = (b * per + s) * 64 + la;
            float m = -1e30f;
            if (a < A) {
                const float* p = cls + (size_t)a * 80 + sub * 4;
                #pragma unroll
                for (int k2 = 0; k2 < 5; k2++) {
                    float4 v = *(const float4*)(p + k2 * 16);
                    m = fmaxf(m, fmaxf(fmaxf(v.x, v.y), fmaxf(v.z, v.w)));
                }
            }
            m = fmaxf(m, __shfl_xor(m, 1, 64));
            m = fmaxf(m, __shfl_xor(m, 2, 64));
            if (sub == 0 && a < A) {
                float s0 = (m > SCORE_THRESH) ? m : -1.0f;
                st_sc(&scores[a], s0);                  // sc1: visible at MALL
                u32 d = order_f32(s0) >> (32 - D0_BITS);
                atomicAdd(&sh.hl[d >> 1], (d & 1) ? 0x10000u : 1u);
            }
        }
        __syncthreads();
        u32* rep = hist0 + (size_t)(b & (NREP - 1)) * D0_BINS;
        for (int i = t; i < D0_BINS / 2; i += 256) {
            u32 v = sh.hl[i];
            if (v & 0xFFFFu) atomicAdd(&rep[2 * i],     v & 0xFFFFu);   // memory-side RMW
            if (v >> 16)     atomicAdd(&rep[2 * i + 1], v >> 16);
        }
    } else {
        u32* rep = hist0 + (size_t)(b & (NREP - 1)) * D0_BINS;
        for (int a = gid; a < A; a += gstride) {
            const float* p = cls + (size_t)a * C;
            float m = -1e30f;
            for (int c = 0; c < C; c++) m = fmaxf(m, p[c]);
            float s0 = (m > SCORE_THRESH) ? m : -1.0f;
            st_sc(&scores[a], s0);
            atomicAdd(&rep[order_f32(s0) >> (32 - D0_BITS)], 1u);
        }
    }
    // All blocks wait: after bar0-go, every block's scores are at the
    // coherence point -> the prefetch below is safe.
    gbar(barr, 0, b, gsz, true);

    // ---------- S2: scan0 (block 0) ∥ prefetch (blocks >0) ----------
    if (b == 0) {
        u32 cnt[32];
        #pragma unroll
        for (int i = 0; i < 32; i++) cnt[i] = 0;
        const uint4* hp = (const uint4*)hist0;
        #pragma unroll
        for (int r = 0; r < NREP; r++) {
            #pragma unroll
            for (int i = 0; i < 8; i++) {
                uint4 v = hp[r * (D0_BINS / 4) + t * 8 + i];
                cnt[4*i]   += v.x; cnt[4*i+1] += v.y;
                cnt[4*i+2] += v.z; cnt[4*i+3] += v.w;
            }
        }
        u32 s = 0;
        #pragma unroll
        for (int i = 0; i < 32; i++) s += cnt[i];
        u32 x = s;   // suffix-inclusive within wave (higher lane = higher bins)
        for (int off = 1; off < 64; off <<= 1) {
            u32 v = (u32)__shfl_down((int)x, off, 64);
            if (lane + off < 64) x += v;
        }
        if (lane == 0) sh.wtot[wv] = x;
        __syncthreads();
        u32 above = x - s;
        for (int w = wv + 1; w < 4; w++) above += sh.wtot[w];
        if (above < TOP_K && above + s >= TOP_K) {
            u32 cum = above;
            for (int i = 31; i >= 0; i--) {
                cum += cnt[i];
                if (cum >= TOP_K) {
                    st_sc(&state[1 * 32], (u32)(t * 32 + i));
                    st_sc(&state[0 * 32], TOP_K - (cum - cnt[i]));
                    break;
                }
            }
        }
    } else {
        // Warm this block's S3/S5 score slice into L1/L2 while block 0 scans.
        float acc = 0.0f;
        for (int a = gid; a < A; a += gstride) acc += scores[a];
        asm volatile("" :: "v"(acc));     // keep the loads alive
    }
    gbar(barr, 1, b, gsz, true);             // everyone needs d0cut

    // ---------- S3: pass-1 histogram (bits [18:3] of keys in cut d0 bin) ----------
    {
        u32 d0cut = state[1 * 32];           // first cached read of this line
        for (int a = gid; a < A; a += gstride) {
            u32 key = order_f32(scores[a]);  // L1/L2 hit (prefetched)
            if ((key >> (32 - D0_BITS)) == d0cut)
                atomicAdd(&hist1[(key >> 3) & 0xFFFFu], 1u);
        }
    }
    gbar(barr, 2, b, gsz, b == 0);           // only block 0 (S4) consumes hist1

    // ---------- S4: scan1 (block 0): d1 cut for k=k_rem ----------
    if (b == 0) {
        u32 k = state[0 * 32];
        const uint4* hp = (const uint4*)hist1;  // strip = bins [t*256, t*256+256)
        u32 chk[8]; u32 s = 0;
        #pragma unroll
        for (int c = 0; c < 8; c++) {
            u32 cs = 0;
            #pragma unroll
            for (int i = 0; i < 8; i++) {
                uint4 v = hp[t * 64 + c * 8 + i];
                cs += v.x + v.y + v.z + v.w;
            }
            chk[c] = cs; s += cs;
        }
        u32 x = s;
        for (int off = 1; off < 64; off <<= 1) {
            u32 v = (u32)__shfl_down((int)x, off, 64);
            if (lane + off < 64) x += v;
        }
        if (lane == 0) sh.wtot[wv] = x;
        __syncthreads();
        u32 above = x - s;
        for (int w = wv + 1; w < 4; w++) above += sh.wtot[w];
        if (above < k && above + s >= k) {
            u32 cum = above;
            bool done = false;
            for (int c = 7; c >= 0 && !done; c--) {
                if (cum + chk[c] >= k) {        // cut is inside chunk c
                    for (int i = 7; i >= 0 && !done; i--) {
                        uint4 v = hp[t * 64 + c * 8 + i];
                        u32 vv[4] = {v.x, v.y, v.z, v.w};
                        for (int q = 3; q >= 0 && !done; q--) {
                            cum += vv[q];
                            if (cum >= k) {
                                st_sc(&state[2 * 32], (u32)(t * 256 + c * 32 + i * 4 + q));
                                done = true;
                            }
                        }
                    }
                } else cum += chk[c];
            }
        }
    }
    gbar(barr, 3, b, gsz, true);             // everyone needs d1cut

    // ---------- S5: compact (pfx29 >= cut), two-sweep, ONE atomic per block ----------
    {
        u32 cut = (state[1 * 32] << 16) | state[2 * 32];
        int nr = (A + gstride - 1) / gstride;
        // sweep 1: count (scores are L1/L2-warm)
        u32 mycnt = 0;
        for (int r = 0; r < nr; r++) {
            int a = gid + r * gstride;
            mycnt += ((a < A) && ((order_f32(scores[a]) >> 3) >= cut)) ? 1u : 0u;
        }
        u32 wc = mycnt;
        wc += (u32)__shfl_xor((int)wc, 1, 64);
        wc += (u32)__shfl_xor((int)wc, 2, 64);
        wc += (u32)__shfl_xor((int)wc, 4, 64);
        wc += (u32)__shfl_xor((int)wc, 8, 64);
        wc += (u32)__shfl_xor((int)wc, 16, 64);
        wc += (u32)__shfl_xor((int)wc, 32, 64);
        if (lane == 0) sh.cmp.wcnt[wv] = wc;
        __syncthreads();
        if (t == 0) {
            u32 s = 0;
            #pragma unroll
            for (int w = 0; w < 4; w++) { sh.cmp.wbase[w] = s; s += sh.cmp.wcnt[w]; }
            sh.cmp.bbase = s ? atomicAdd(&state[5 * 32], s) : 0u;
        }
        __syncthreads();
        // sweep 2: ordered write (order within block irrelevant: keys unique,
        // rank-sort later is order-independent; n << CAND_CAP so no drops)
        u32 off = sh.cmp.bbase + sh.cmp.wbase[wv];
        for (int r = 0; r < nr; r++) {
            int a = gid + r * gstride;
            bool pass = (a < A) && ((order_f32(scores[a]) >> 3) >= cut);
            u64 mask = __ballot(pass ? 1 : 0);
            if (pass) {
                u32 pos = off + (u32)__popcll(mask & ((1ull << lane) - 1ull));
                if (pos < CAND_CAP) st_sc(&cand[pos], (u32)a);
            }
            off += (u32)__popcll(mask);
        }
    }
    gbar(barr, 4, b, gsz, b < CAND_CAP / 8); // S6 participants wait

    // ---------- S6: exact parallel rank + decode ----------
    if (b < CAND_CAP / 8) {
        int n = (int)state[5 * 32]; if (n > CAND_CAP) n = CAND_CAP;   // first-touch
        u64 kj[8];                           // this thread's j-strip of keys
        #pragma unroll
        for (int q = 0; q < 8; q++) {
            int j = t * 8 + q;
            u64 kk = 0ull;                   // pads never outrank real keys
            if (j < n) {
                u32 a = cand[j];             // first-touch -> MALL, then cached
                kk = ((u64)order_f32(scores[a]) << 32) | (u64)(0xFFFFFFFFu - a);
            }
            kj[q] = kk;
        }
        for (int bb = b; bb < CAND_CAP / 8; bb += G) {
            if (t < 8) {
                int c = bb * 8 + t;
                u64 ck = 0ull;
                if (c < n) {
                    u32 a = cand[c];
                    ck = ((u64)order_f32(scores[a]) << 32) | (u64)(0xFFFFFFFFu - a);
                }
                sh.rank.ckeys[t] = ck;
            }
            __syncthreads();
            u64 ck[8];
            #pragma unroll
            for (int q = 0; q < 8; q++) ck[q] = sh.rank.ckeys[q];
            u32 cnt8[8] = {0,0,0,0,0,0,0,0};
            #pragma unroll
            for (int q = 0; q < 8; q++) {
                u64 kq = kj[q];
                #pragma unroll
                for (int q2 = 0; q2 < 8; q2++) cnt8[q2] += (kq > ck[q2]) ? 1u : 0u;
            }
            #pragma unroll
            for (int q2 = 0; q2 < 8; q2++) {
                u32 x = cnt8[q2];
                x += (u32)__shfl_xor((int)x, 1, 64);
                x += (u32)__shfl_xor((int)x, 2, 64);
                x += (u32)__shfl_xor((int)x, 4, 64);
                x += (u32)__shfl_xor((int)x, 8, 64);
                x += (u32)__shfl_xor((int)x, 16, 64);
                x += (u32)__shfl_xor((int)x, 32, 64);
                if (lane == 0) sh.rank.wpart[wv][q2] = x;
            }
            __syncthreads();
            if (t < 8) {
                int c = bb * 8 + t;
                if (c < n) {
                    u32 rank = sh.rank.wpart[0][t] + sh.rank.wpart[1][t]
                             + sh.rank.wpart[2][t] + sh.rank.wpart[3][t];
                    if (rank < TOP_K) {
                        u32 a = cand[c];
                        st_sc(&sidx[rank], a);
                        st_sc(&sscore[rank], scores[a]);
                        float4 an = *(const float4*)(anchors + (size_t)a * 4);
                        float4 rg = *(const float4*)(regs + (size_t)a * 4);
                        float aw = an.z - an.x, ah = an.w - an.y;
                        float acx = an.x + 0.5f * aw, acy = an.y + 0.5f * ah;
                        float pcx = acx + (rg.x * 0.1f) * aw;
                        float pcy = acy + (rg.y * 0.1f) * ah;
                        float pw = expf(rg.z * 0.2f) * aw;
                        float ph = expf(rg.w * 0.2f) * ah;
                        float W = (float)(*pW), H = (float)(*pH);
                        st_sc(&cbox[rank * 4 + 0], fminf(fmaxf(pcx - 0.5f * pw, 0.0f), W));
                        st_sc(&cbox[rank * 4 + 1], fminf(fmaxf(pcy - 0.5f * ph, 0.0f), H));
                        st_sc(&cbox[rank * 4 + 2], fminf(fmaxf(pcx + 0.5f * pw, 0.0f), W));
                        st_sc(&cbox[rank * 4 + 3], fminf(fmaxf(pcy + 0.5f * ph, 0.0f), H));
                    }
                }
            }
            __syncthreads();
        }
    }
    gbar(barr, 5, b, gsz, b * 4 < TOP_K);    // S7 participants wait

    // ---------- S7: IoU suppression bit-matrix (wave per row) ----------
    {
        const float4* B4 = (const float4*)cbox;   // first-touch -> MALL, then cached
        for (int i = b * 4 + wv; i < TOP_K; i += G * 4) {
            float4 bi = B4[i];
            float ai = fmaxf(bi.z - bi.x, 0.0f) * fmaxf(bi.w - bi.y, 0.0f);
            u64 any = 0ull;
            for (int w = 0; w < 16; w++) {
                int j = w * 64 + lane;
                bool sup = false;
                if (j < TOP_K && j > i) {
                    float4 bj = B4[j];
                    float aj = fmaxf(bj.z - bj.x, 0.0f) * fmaxf(bj.w - bj.y, 0.0f);
                    float xx1 = fmaxf(bi.x, bj.x), yy1 = fmaxf(bi.y, bj.y);
                    float xx2 = fminf(bi.z, bj.z), yy2 = fminf(bi.w, bj.w);
                    float inter = fmaxf(xx2 - xx1, 0.0f) * fmaxf(yy2 - yy1, 0.0f);
                    float iou = inter / (ai + aj - inter + 1e-8f);
                    sup = iou > IOU_THRESH;
                }
                u64 mask = __ballot(sup ? 1 : 0);
                if (lane == 0) { st_sc(&M[(size_t)i * 16 + w], mask); any |= mask; }
            }
            if (lane == 0) st_sc(&rflag[i], (any != 0ull) ? 1u : 0u);
        }
    }
    gbar(barr, 6, b, gsz, b == 0);           // only block 0 (S8) consumes

    // ---------- S8: greedy NMS over active rows + finalize (block 0) ----------
    if (b == 0) {
        {
            u32 nb = 0;
            int j0 = 4 * t;
            #pragma unroll
            for (int q = 0; q < 4; q++) {
                int j = j0 + q;
                if (j < TOP_K && sscore[j] > SCORE_THRESH) nb |= (1u << q);
            }
            sh.nms.nib[t] = nb;
        }
        u32 flags = 0; int cnt = 0;
        {
            int r0 = 4 * t;
            #pragma unroll
            for (int q = 0; q < 4; q++) {
                int r = r0 + q;
                if (r < TOP_K && rflag[r]) { flags |= (1u << q); cnt++; }
            }
        }
        int x = cnt;
        for (int off = 1; off < 64; off <<= 1) {
            int v = __shfl_up(x, off, 64);
            if (lane >= off) x += v;
        }
        if (lane == 63) sh.nms.wsum[wv] = (u32)x;
        __syncthreads();
        if (t < 16) {
            u64 w = 0;
            for (int m2 = 0; m2 < 16; m2++)
                w |= ((u64)sh.nms.nib[t * 16 + m2]) << (4 * m2);
            sh.nms.keepS[t] = w;
        }
        int base = 0;
        for (int w = 0; w < wv; w++) base += (int)sh.nms.wsum[w];
        int pos = base + x - cnt;
        {
            int r0 = 4 * t;
            #pragma unroll
            for (int q = 0; q < 4; q++)
                if (flags & (1u << q)) sh.nms.act[pos++] = r0 + q;
        }
        if (t == 0) {
            int na = 0;
            for (int w = 0; w < 4; w++) na += (int)sh.nms.wsum[w];
            sh.nms.nactS = na;
        }
        __syncthreads();
        int nact = sh.nms.nactS;
        int nchunks = (nact + NMS_CHUNK - 1) / NMS_CHUNK;

        // Double-buffered chunked greedy: waves 1-3 stage chunk ci+1 from MALL
        // while wave 0 runs the (inherently serial) keep-chain on chunk ci.
        if (nchunks > 0) {
            int cn0 = (nact < NMS_CHUNK) ? nact : NMS_CHUNK;
            for (int i = t; i < cn0 * 16; i += 256) {
                int row = sh.nms.act[i >> 4];
                sh.nms.Ml[i] = M[(size_t)row * 16 + (i & 15)];
            }
        }
        __syncthreads();
        u64 kp = (wv == 0 && lane < 16) ? sh.nms.keepS[lane] : 0ull;
        for (int ci = 0; ci < nchunks; ci++) {
            int c0 = ci * NMS_CHUNK;
            int cn = (nact - c0 < NMS_CHUNK) ? (nact - c0) : NMS_CHUNK;
            int cur = (ci & 1) * (NMS_CHUNK * 16);
            if (ci + 1 < nchunks && t >= 64) {
                int c0n = c0 + NMS_CHUNK;
                int cnn = (nact - c0n < NMS_CHUNK) ? (nact - c0n) : NMS_CHUNK;
                int nxt = ((ci + 1) & 1) * (NMS_CHUNK * 16);
                for (int i = t - 64; i < cnn * 16; i += 192) {
                    int row = sh.nms.act[c0n + (i >> 4)];
                    sh.nms.Ml[nxt + i] = M[(size_t)row * 16 + (i & 15)];
                }
            }
            if (wv == 0) {
                for (int k = 0; k < cn; k++) {
                    int i = sh.nms.act[c0 + k];
                    u64 kw = __shfl(kp, i >> 6, 64);
                    if ((kw >> (i & 63)) & 1ull) {
                        u64 m2 = (lane < 16) ? sh.nms.Ml[cur + k * 16 + lane] : 0ull;
                        kp &= ~m2;
                    }
                }
            }
            __syncthreads();
        }
        if (wv == 0 && lane < 16) sh.nms.keepS[lane] = kp;
        __syncthreads();

        if (t == 0) {
            int cnt2 = 0;
            for (int w = 0; w < 16 && cnt2 < MAX_DET; w++) {
                u64 kw = sh.nms.keepS[w];
                while (kw && cnt2 < MAX_DET) {
                    int bbit = __ffsll((unsigned long long)kw) - 1;
                    sh.nms.det[cnt2++] = w * 64 + bbit;
                    kw &= kw - 1;
                }
            }
            for (; cnt2 < MAX_DET; cnt2++) sh.nms.det[cnt2] = -1;
        }
        __syncthreads();
        if (t < MAX_DET) {
            int i = sh.nms.det[t];
            if (i >= 0) {
                u32 a = sidx[i];
                const float* p = cls + (size_t)a * C;
                float best = -1e30f; int bc = 0;
                if (C == 80) {
                    #pragma unroll
                    for (int c4 = 0; c4 < 20; c4++) {
                        float4 v = *(const float4*)(p + c4 * 4);
                        if (v.x > best) { best = v.x; bc = c4 * 4; }
                        if (v.y > best) { best = v.y; bc = c4 * 4 + 1; }
                        if (v.z > best) { best = v.z; bc = c4 * 4 + 2; }
                        if (v.w > best) { best = v.w; bc = c4 * 4 + 3; }
                    }
                } else {
                    best = p[0]; bc = 0;
                    for (int c = 1; c < C; c++) {
                        float v = p[c];
                        if (v > best) { best = v; bc = c; }
                    }
                }
                out[t] = best;
                out[MAX_DET + t] = (float)bc;
                out[2 * MAX_DET + t * 4 + 0] = cbox[i * 4 + 0];
                out[2 * MAX_DET + t * 4 + 1] = cbox[i * 4 + 1];
                out[2 * MAX_DET + t * 4 + 2] = cbox[i * 4 + 2];
                out[2 * MAX_DET + t * 4 + 3] = cbox[i * 4 + 3];
            } else {
                out[t] = 0.0f;
                out[MAX_DET + t] = -1.0f;
                out[2 * MAX_DET + t * 4 + 0] = 0.0f;
                out[2 * MAX_DET + t * 4 + 1] = 0.0f;
                out[2 * MAX_DET + t * 4 + 2] = 0.0f;
                out[2 * MAX_DET + t * 4 + 3] = 0.0f;
            }
        }
    }
}

extern "C" void kernel_launch(void* const* d_in, const int* in_sizes, int n_in,
                              void* d_out, int out_size, void* d_ws, size_t ws_size,
                              hipStream_t stream) {
    (void)n_in; (void)out_size; (void)ws_size;
    const float* cls     = (const float*)d_in[0];
    const float* regs    = (const float*)d_in[1];
    const float* anchors = (const float*)d_in[2];
    const int*   pH      = (const int*)d_in[3];
    const int*   pW      = (const int*)d_in[4];
    int A = in_sizes[1] / 4;
    int C = in_sizes[0] / A;

    // grid = 2 blocks/CU, multiple of 8 (barrier tree groups):
    // co-residency guaranteed (37.6KB LDS -> 2 blocks/CU, launch_bounds(256,2)).
    static int nCU = 0;
    if (nCU <= 0) {
        int dev = 0;
        hipGetDevice(&dev);
        hipDeviceGetAttribute(&nCU, hipDeviceAttributeMultiprocessorCount, dev);
        if (nCU <= 0) nCU = 256;
    }
    int G = (2 * nCU) & ~7;
    if (G < 8) G = 8;

    char* ws = (char*)d_ws;
    // Zero hist0 + hist1 + state + barrier tree in one memset; the fill
    // dispatch's completion makes the zeros coherence-point visible.
    hipMemsetAsync(ws, 0, MEMSET_LEN, stream);
    mega<<<dim3(G), dim3(256), 0, stream>>>(cls, regs, anchors, pH, pW, A, C,
                                            ws, (float*)d_out);
}